// Round 6
// baseline (317.330 us; speedup 1.0000x reference)
//
#include <hip/hip_runtime.h>

// TSA_24936580121000 — fused temporal self-attention, MI355X gfx950. Round 6.
// vs R5: PLAIN __launch_bounds__ (the ",4" variants all clamped VGPR to 64 and
// spilled — R3/R4/R5 WRITE inflation). Pipelined persistent-ish blocks:
// 256 blocks x 1024 thr (16 waves, 1 position/wave), each block = one (b,h)
// row = 4 tiles of WT=16. Disjoint LDS regions (stage/qk/out = 150 KiB) so
// tile i+1's global loads overlap tile i's entire compute phase.

#define C_  128
#define T_  16
#define H_  64
#define W_  64
#define HW_ (H_*W_)
#define CO_ 160          // 16 q + 16 k + 128 v
#define WT_ 16           // w positions per tile
#define NTILE 4          // tiles per block (full w row)
#define NBLK 256         // 4 b * 64 h
#define THW (T_*H_*W_)

typedef float  f32x4  __attribute__((ext_vector_type(4)));
typedef short  bf16x4 __attribute__((ext_vector_type(4)));
typedef short  bf16x8 __attribute__((ext_vector_type(8)));

__device__ __forceinline__ unsigned short f2bf(float f) {
    union { float f; unsigned u; } v; v.f = f;
    unsigned r = v.u + 0x7fffu + ((v.u >> 16) & 1u);   // RNE
    return (unsigned short)(r >> 16);
}
__device__ __forceinline__ float bf2f(unsigned short s) {
    union { unsigned u; float f; } v; v.u = ((unsigned)s) << 16;
    return v.f;
}

// ---------------- prepack: fp32 weights -> bf16 W2[160][128], biases b2[160] ----
__global__ __launch_bounds__(256) void tsa_prepack(
        const float* __restrict__ qw, const float* __restrict__ qb,
        const float* __restrict__ kw, const float* __restrict__ kb,
        const float* __restrict__ vw, const float* __restrict__ vb,
        unsigned short* __restrict__ W2, float* __restrict__ b2) {
    int i = blockIdx.x * 256 + threadIdx.x;      // 80*256 == 20480 == 160*128
    int o = i >> 7, c = i & 127;
    float v = (o < 16) ? qw[o * C_ + c] : (o < 32) ? kw[(o - 16) * C_ + c]
                                                   : vw[(o - 32) * C_ + c];
    W2[i] = f2bf(v);
    if (i < CO_) b2[i] = (i < 16) ? qb[i] : (i < 32) ? kb[i - 16] : vb[i - 32];
}

// ---------------- LDS geometry (shorts) — THREE DISJOINT regions ---------------
// stage: [pos=16][t=16][c=128] pos-stride 2184, t-stride 136 -> 34944 sh
// qk:    [pos=16][2][t=16][o=16]                              ->  8192 sh
// out:   [t=16][w=16][c=128]   t-stride 2116, w-stride 132    -> 33856 sh
#define PS 2184
#define TS 136
#define IDX_X(pos, t, c)      ((pos) * PS + (t) * TS + (c))
#define QK_OFF 34944
#define IDX_QK(pos, qk, t, o) (QK_OFF + ((((pos) * 2 + (qk)) * T_ + (t)) * 16) + (o))
#define OUT_OFF 43136
#define OS_W 132
#define OS_T 2116
#define IDX_O(t, w, c)        (OUT_OFF + (t) * OS_T + (w) * OS_W + (c))
#define BUF_SH 76992          // 153984 B <= 160 KiB -> 1 block/CU

// ---------------- main fused kernel --------------------------------------------
__global__ __launch_bounds__(1024) void tsa_main(
        const float* __restrict__ x, const unsigned short* __restrict__ W2,
        const float* __restrict__ b2, const float* __restrict__ gamma,
        float* __restrict__ y) {

    __shared__ __align__(16) unsigned short buf[BUF_SH];

    // XCD-chunked swizzle (nwg=256 % 8 == 0)
    int bid  = blockIdx.x;
    int work = (bid & 7) * (NBLK / 8) + (bid >> 3);
    int b  = work >> 6, h = work & 63;

    const size_t base = (size_t)b * C_ * THW + (size_t)h * W_;
    const float* xb = x + base;
    float*       yb = y + base;

    const int tid = threadIdx.x;
    const int seg = tid & 3;          // 16B segment within the 64B tile w-row
    const int cs  = (tid >> 2) & 127; // channel 0..127
    const int hf  = tid >> 9;         // t-half 0/1
    const float g = gamma[0];

    const int wv  = tid >> 6;         // wave 0..15 -> position wv
    const int lr  = tid & 15;
    const int grp = (tid & 63) >> 4;

    float biasv[10];
    #pragma unroll
    for (int nt = 0; nt < 10; ++nt) biasv[nt] = b2[nt * 16 + lr];

    // ---- prologue: stage tile 0 -------------------------------------------
    {
        const float* xc = xb + (size_t)cs * THW + seg * 4 + hf * 8 * HW_;
        f32x4 xp[8];
        #pragma unroll
        for (int tt = 0; tt < 8; ++tt) xp[tt] = *(const f32x4*)(xc + tt * HW_);
        #pragma unroll
        for (int tt = 0; tt < 8; ++tt)
            #pragma unroll
            for (int e = 0; e < 4; ++e)
                buf[IDX_X(seg * 4 + e, hf * 8 + tt, cs)] = f2bf(xp[tt][e]);
    }
    __syncthreads();

    for (int i = 0; i < NTILE; ++i) {
        const int w0 = i * WT_;

        // ---- afrag from stage (tile i) -----------------------------------
        bf16x8 afrag[4];
        #pragma unroll
        for (int ks = 0; ks < 4; ++ks)
            afrag[ks] = *(const bf16x8*)&buf[IDX_X(wv, lr, ks * 32 + grp * 8)];
        __syncthreads();   // Ba: stage region free for tile i+1

        // ---- issue tile i+1 global loads (fly during all of P2) ----------
        f32x4 xn[8];
        if (i + 1 < NTILE) {
            const float* xc = xb + (w0 + WT_) + (size_t)cs * THW + seg * 4 + hf * 8 * HW_;
            #pragma unroll
            for (int tt = 0; tt < 8; ++tt) xn[tt] = *(const f32x4*)(xc + tt * HW_);
        }

        // ---- P2: qkv projection (mfma 16x16x32 bf16), 1 position/wave ----
        bf16x4 vreg[8];
        #pragma unroll
        for (int nt = 0; nt < 10; ++nt) {
            f32x4 acc = (f32x4){0.f, 0.f, 0.f, 0.f};
            #pragma unroll
            for (int ks = 0; ks < 4; ++ks) {
                bf16x8 wf = *(const bf16x8*)&W2[(nt * 16 + lr) * C_ + ks * 32 + grp * 8];
                acc = __builtin_amdgcn_mfma_f32_16x16x32_bf16(afrag[ks], wf, acc, 0, 0, 0);
            }
            if (nt < 2) {                 // q/k -> LDS (cross-lane transpose)
                #pragma unroll
                for (int r = 0; r < 4; ++r)
                    buf[IDX_QK(wv, nt, grp * 4 + r, lr)] = f2bf(acc[r] + biasv[nt]);
            } else {                      // v -> regs: proj D-layout == PV A-layout
                bf16x4 pk;
                #pragma unroll
                for (int r = 0; r < 4; ++r) pk[r] = (short)f2bf(acc[r] + biasv[nt]);
                vreg[nt - 2] = pk;
            }
        }

        // ---- write tile i+1 to stage (waits its loads; overlap done) -----
        if (i + 1 < NTILE) {
            #pragma unroll
            for (int tt = 0; tt < 8; ++tt)
                #pragma unroll
                for (int e = 0; e < 4; ++e)
                    buf[IDX_X(seg * 4 + e, hf * 8 + tt, cs)] = f2bf(xn[tt][e]);
        }
        __syncthreads();   // Bb: qk + next stage visible

        // ---- P3: scores^T -> softmax -> PV (pos = wv) --------------------
        bf16x4 obf[8];
        {
            bf16x4 kf = *(const bf16x4*)&buf[IDX_QK(wv, 1, lr, grp * 4)];
            bf16x4 qf = *(const bf16x4*)&buf[IDX_QK(wv, 0, lr, grp * 4)];
            f32x4 s = (f32x4){0.f, 0.f, 0.f, 0.f};
            s = __builtin_amdgcn_mfma_f32_16x16x16bf16_1k(kf, qf, s, 0, 0, 0);
            float mx = fmaxf(fmaxf(s[0], s[1]), fmaxf(s[2], s[3]));
            mx = fmaxf(mx, __shfl_xor(mx, 16));
            mx = fmaxf(mx, __shfl_xor(mx, 32));
            float e0 = __expf(s[0] - mx), e1 = __expf(s[1] - mx);
            float e2 = __expf(s[2] - mx), e3 = __expf(s[3] - mx);
            float sm = e0 + e1 + e2 + e3;
            sm += __shfl_xor(sm, 16);
            sm += __shfl_xor(sm, 32);
            float inv = 1.0f / sm;
            bf16x4 pf;
            pf[0] = (short)f2bf(e0 * inv); pf[1] = (short)f2bf(e1 * inv);
            pf[2] = (short)f2bf(e2 * inv); pf[3] = (short)f2bf(e3 * inv);
            #pragma unroll
            for (int ct = 0; ct < 8; ++ct) {
                f32x4 z = (f32x4){0.f, 0.f, 0.f, 0.f};
                z = __builtin_amdgcn_mfma_f32_16x16x16bf16_1k(vreg[ct], pf, z, 0, 0, 0);
                bf16x4 ob;
                #pragma unroll
                for (int r = 0; r < 4; ++r) ob[r] = (short)f2bf(z[r]);
                obf[ct] = ob;
            }
        }

        // ---- pre-issue residual re-read (tile i, L2-hot) -----------------
        f32x4 xr[8];
        {
            const float* xc = xb + w0 + (size_t)cs * THW + seg * 4 + hf * 8 * HW_;
            #pragma unroll
            for (int tt = 0; tt < 8; ++tt) xr[tt] = *(const f32x4*)(xc + tt * HW_);
        }

        // ---- spill outT -> out LDS [t][w][c] -----------------------------
        #pragma unroll
        for (int ct = 0; ct < 8; ++ct)
            *(bf16x4*)&buf[IDX_O(lr, wv, ct * 16 + grp * 4)] = obf[ct];
        __syncthreads();   // Bd

        // ---- phase 5: y = gamma*out + x (exact fp32 residual) ------------
        {
            float* yr = yb + w0 + (size_t)cs * THW + seg * 4 + hf * 8 * HW_;
            #pragma unroll
            for (int tt = 0; tt < 8; ++tt) {
                int t = hf * 8 + tt;
                f32x4 rv;
                #pragma unroll
                for (int e = 0; e < 4; ++e)
                    rv[e] = fmaf(g, bf2f(buf[IDX_O(t, seg * 4 + e, cs)]), xr[tt][e]);
                *(f32x4*)(yr + tt * HW_) = rv;
            }
        }
        // no trailing barrier: out-region reuse is fenced by next iter's Ba+Bb
    }
}

// ---------------- launch --------------------------------------------------------
extern "C" void kernel_launch(void* const* d_in, const int* in_sizes, int n_in,
                              void* d_out, int out_size, void* d_ws, size_t ws_size,
                              hipStream_t stream) {
    const float* x  = (const float*)d_in[0];
    const float* qw = (const float*)d_in[1];
    const float* qb = (const float*)d_in[2];
    const float* kw = (const float*)d_in[3];
    const float* kb = (const float*)d_in[4];
    const float* vw = (const float*)d_in[5];
    const float* vb = (const float*)d_in[6];
    const float* gm = (const float*)d_in[7];
    float* y = (float*)d_out;

    unsigned short* W2 = (unsigned short*)d_ws;                  // 160*128 bf16
    float* b2 = (float*)((char*)d_ws + CO_ * C_ * sizeof(unsigned short));

    tsa_prepack<<<80, 256, 0, stream>>>(qw, qb, kw, kb, vw, vb, W2, b2);
    tsa_main<<<NBLK, 1024, 0, stream>>>(x, W2, b2, gm, y);
}

// Round 7
// 289.376 us; speedup vs baseline: 1.0966x; 1.0966x over previous
//
#include <hip/hip_runtime.h>

// TSA_24936580121000 — fused temporal self-attention, MI355X gfx950. Round 7.
// R6's pipelined 4-tile structure, rebuilt spill-proof for the observed 64-VGPR
// allocator cap: NO long-lived register arrays. Next-tile staging and residual
// re-reads use rolling 4-deep f32x4 windows with constant indices (full unroll),
// retired incrementally under compute. Bias lives in LDS. 1 block/CU, 16 waves.

#define C_  128
#define T_  16
#define H_  64
#define W_  64
#define HW_ (H_*W_)
#define CO_ 160          // 16 q + 16 k + 128 v
#define WT_ 16           // w positions per tile
#define NTILE 4          // tiles per block = one (b,h) row
#define NBLK 256         // 4 b * 64 h
#define THW (T_*H_*W_)

typedef float  f32x4  __attribute__((ext_vector_type(4)));
typedef short  bf16x4 __attribute__((ext_vector_type(4)));
typedef short  bf16x8 __attribute__((ext_vector_type(8)));

__device__ __forceinline__ unsigned short f2bf(float f) {
    union { float f; unsigned u; } v; v.f = f;
    unsigned r = v.u + 0x7fffu + ((v.u >> 16) & 1u);   // RNE
    return (unsigned short)(r >> 16);
}
__device__ __forceinline__ float bf2f(unsigned short s) {
    union { unsigned u; float f; } v; v.u = ((unsigned)s) << 16;
    return v.f;
}

// ---------------- prepack: fp32 weights -> bf16 W2[160][128], biases b2[160] ----
__global__ __launch_bounds__(256) void tsa_prepack(
        const float* __restrict__ qw, const float* __restrict__ qb,
        const float* __restrict__ kw, const float* __restrict__ kb,
        const float* __restrict__ vw, const float* __restrict__ vb,
        unsigned short* __restrict__ W2, float* __restrict__ b2) {
    int i = blockIdx.x * 256 + threadIdx.x;      // 80*256 == 20480 == 160*128
    int o = i >> 7, c = i & 127;
    float v = (o < 16) ? qw[o * C_ + c] : (o < 32) ? kw[(o - 16) * C_ + c]
                                                   : vw[(o - 32) * C_ + c];
    W2[i] = f2bf(v);
    if (i < CO_) b2[i] = (i < 16) ? qb[i] : (i < 32) ? kb[i - 16] : vb[i - 32];
}

// ---------------- LDS regions (shorts), all disjoint ---------------------------
// stage: [pos=16][t=16][c=128] pos-stride 2184, t-stride 136 -> 34944 sh
// qk:    [pos=16][2][t=16][o=16]                              ->  8192 sh
// out:   [t=16][w=16][c=128]   t-stride 2116, w-stride 132    -> 33856 sh
// bias:  f32[160]                                             ->   320 sh
#define PS 2184
#define TS 136
#define IDX_X(pos, t, c)      ((pos) * PS + (t) * TS + (c))
#define QK_OFF 34944
#define IDX_QK(pos, qk, t, o) (QK_OFF + ((((pos) * 2 + (qk)) * T_ + (t)) * 16) + (o))
#define OUT_OFF 43136
#define OS_W 132
#define OS_T 2116
#define IDX_O(t, w, c)        (OUT_OFF + (t) * OS_T + (w) * OS_W + (c))
#define BIAS_OFF 76992
#define BUF_SH 77312          // 154624 B <= 160 KiB -> 1 block/CU

// ---------------- main fused kernel --------------------------------------------
__global__ __launch_bounds__(1024) void tsa_main(
        const float* __restrict__ x, const unsigned short* __restrict__ W2,
        const float* __restrict__ b2, const float* __restrict__ gamma,
        float* __restrict__ y) {

    __shared__ __align__(16) unsigned short buf[BUF_SH];
    float* bias_lds = (float*)&buf[BIAS_OFF];

    // XCD-chunked swizzle (nwg=256 % 8 == 0)
    int bid  = blockIdx.x;
    int work = (bid & 7) * (NBLK / 8) + (bid >> 3);
    int b  = work >> 6, h = work & 63;

    const size_t base = (size_t)b * C_ * THW + (size_t)h * W_;
    const float* xb = x + base;
    float*       yb = y + base;

    const int tid = threadIdx.x;
    const int seg = tid & 3;          // 16B segment of the 64B tile w-row
    const int cs  = (tid >> 2) & 127; // channel
    const int hf  = tid >> 9;         // t-half 0/1
    const float g = gamma[0];

    const int wv  = tid >> 6;         // wave 0..15 -> position wv
    const int lr  = tid & 15;
    const int grp = (tid & 63) >> 4;

    if (tid < CO_) bias_lds[tid] = b2[tid];

    // ---- prologue: stage tile 0 (8-deep transient batch) -------------------
    {
        const float* xc = xb + (size_t)cs * THW + seg * 4 + hf * 8 * HW_;
        f32x4 xp[8];
        #pragma unroll
        for (int t = 0; t < 8; ++t) xp[t] = *(const f32x4*)(xc + t * HW_);
        #pragma unroll
        for (int t = 0; t < 8; ++t)
            #pragma unroll
            for (int e = 0; e < 4; ++e)
                buf[IDX_X(seg * 4 + e, hf * 8 + t, cs)] = f2bf(xp[t][e]);
    }
    __syncthreads();

    for (int i = 0; i < NTILE; ++i) {
        const int w0 = i * WT_;
        const bool hasNext = (i + 1 < NTILE);

        // ---- afrag from stage (tile i) -----------------------------------
        bf16x8 afrag[4];
        #pragma unroll
        for (int ks = 0; ks < 4; ++ks)
            afrag[ks] = *(const bf16x8*)&buf[IDX_X(wv, lr, ks * 32 + grp * 8)];
        __syncthreads();   // Ba: stage region free for tile i+1

        // ---- rolling 4-deep next-tile loads (retired inside the nt loop) --
        const float* xn = xb + (w0 + WT_) + (size_t)cs * THW + seg * 4 + hf * 8 * HW_;
        f32x4 ld[4];
        if (hasNext) {
            #pragma unroll
            for (int k = 0; k < 4; ++k) ld[k] = *(const f32x4*)(xn + k * HW_);
        }

        // ---- P2: qkv projection (mfma 16x16x32 bf16), 1 position/wave ----
        bf16x4 vreg[8];
        #pragma unroll
        for (int nt = 0; nt < 10; ++nt) {
            f32x4 acc = (f32x4){0.f, 0.f, 0.f, 0.f};
            #pragma unroll
            for (int ks = 0; ks < 4; ++ks) {
                bf16x8 wf = *(const bf16x8*)&W2[(nt * 16 + lr) * C_ + ks * 32 + grp * 8];
                acc = __builtin_amdgcn_mfma_f32_16x16x32_bf16(afrag[ks], wf, acc, 0, 0, 0);
            }
            float bv = bias_lds[nt * 16 + lr];
            if (nt < 2) {                 // q/k -> LDS (cross-lane transpose)
                #pragma unroll
                for (int r = 0; r < 4; ++r)
                    buf[IDX_QK(wv, nt, grp * 4 + r, lr)] = f2bf(acc[r] + bv);
            } else {                      // v -> regs: proj D-layout == PV A-layout
                bf16x4 pk;
                #pragma unroll
                for (int r = 0; r < 4; ++r) pk[r] = (short)f2bf(acc[r] + bv);
                vreg[nt - 2] = pk;
            }
            // retire rolled load t=nt-2 into stage; reissue slot for t=nt+2
            if (hasNext && nt >= 2) {
                const int t = nt - 2;                  // 0..7, constant (unrolled)
                f32x4 v = ld[t & 3];
                #pragma unroll
                for (int e = 0; e < 4; ++e)
                    buf[IDX_X(seg * 4 + e, hf * 8 + t, cs)] = f2bf(v[e]);
                if (t + 4 < 8) ld[t & 3] = *(const f32x4*)(xn + (t + 4) * HW_);
            }
        }
        __syncthreads();   // Bb: qk + next-tile stage visible

        // ---- P3: scores^T -> softmax -> PV (pos = wv) --------------------
        bf16x4 obf[8];
        {
            bf16x4 kf = *(const bf16x4*)&buf[IDX_QK(wv, 1, lr, grp * 4)];
            bf16x4 qf = *(const bf16x4*)&buf[IDX_QK(wv, 0, lr, grp * 4)];
            f32x4 s = (f32x4){0.f, 0.f, 0.f, 0.f};
            s = __builtin_amdgcn_mfma_f32_16x16x16bf16_1k(kf, qf, s, 0, 0, 0);
            float mx = fmaxf(fmaxf(s[0], s[1]), fmaxf(s[2], s[3]));
            mx = fmaxf(mx, __shfl_xor(mx, 16));
            mx = fmaxf(mx, __shfl_xor(mx, 32));
            float e0 = __expf(s[0] - mx), e1 = __expf(s[1] - mx);
            float e2 = __expf(s[2] - mx), e3 = __expf(s[3] - mx);
            float sm = e0 + e1 + e2 + e3;
            sm += __shfl_xor(sm, 16);
            sm += __shfl_xor(sm, 32);
            float inv = 1.0f / sm;
            bf16x4 pf;
            pf[0] = (short)f2bf(e0 * inv); pf[1] = (short)f2bf(e1 * inv);
            pf[2] = (short)f2bf(e2 * inv); pf[3] = (short)f2bf(e3 * inv);
            #pragma unroll
            for (int ct = 0; ct < 8; ++ct) {
                f32x4 z = (f32x4){0.f, 0.f, 0.f, 0.f};
                z = __builtin_amdgcn_mfma_f32_16x16x16bf16_1k(vreg[ct], pf, z, 0, 0, 0);
                bf16x4 ob;
                #pragma unroll
                for (int r = 0; r < 4; ++r) ob[r] = (short)f2bf(z[r]);
                obf[ct] = ob;
            }
        }

        // ---- P4: pre-issue rolling residual loads, then spill outT -------
        const float* xc = xb + w0 + (size_t)cs * THW + seg * 4 + hf * 8 * HW_;
        f32x4 xr[4];
        #pragma unroll
        for (int k = 0; k < 4; ++k) xr[k] = *(const f32x4*)(xc + k * HW_);

        #pragma unroll
        for (int ct = 0; ct < 8; ++ct)
            *(bf16x4*)&buf[IDX_O(lr, wv, ct * 16 + grp * 4)] = obf[ct];
        __syncthreads();   // Bc

        // ---- P5: y = gamma*out + x (exact fp32 residual), rolling loads ---
        {
            float* yr = yb + w0 + (size_t)cs * THW + seg * 4 + hf * 8 * HW_;
            #pragma unroll
            for (int tt = 0; tt < 8; ++tt) {
                const int t = hf * 8 + tt;
                f32x4 xv = xr[tt & 3];
                if (tt + 4 < 8) xr[tt & 3] = *(const f32x4*)(xc + (tt + 4) * HW_);
                f32x4 rv;
                #pragma unroll
                for (int e = 0; e < 4; ++e)
                    rv[e] = fmaf(g, bf2f(buf[IDX_O(t, seg * 4 + e, cs)]), xv[e]);
                *(f32x4*)(yr + tt * HW_) = rv;
            }
        }
        // out-region reuse and stage reuse are fenced by next iter's Ba/Bb.
    }
}

// ---------------- launch --------------------------------------------------------
extern "C" void kernel_launch(void* const* d_in, const int* in_sizes, int n_in,
                              void* d_out, int out_size, void* d_ws, size_t ws_size,
                              hipStream_t stream) {
    const float* x  = (const float*)d_in[0];
    const float* qw = (const float*)d_in[1];
    const float* qb = (const float*)d_in[2];
    const float* kw = (const float*)d_in[3];
    const float* kb = (const float*)d_in[4];
    const float* vw = (const float*)d_in[5];
    const float* vb = (const float*)d_in[6];
    const float* gm = (const float*)d_in[7];
    float* y = (float*)d_out;

    unsigned short* W2 = (unsigned short*)d_ws;                  // 160*128 bf16
    float* b2 = (float*)((char*)d_ws + CO_ * C_ * sizeof(unsigned short));

    tsa_prepack<<<80, 256, 0, stream>>>(qw, qb, kw, kb, vw, vb, W2, b2);
    tsa_main<<<NBLK, 1024, 0, stream>>>(x, W2, b2, gm, y);
}

// Round 8
// 104.647 us; speedup vs baseline: 3.0324x; 2.7652x over previous
//
#include <hip/hip_runtime.h>

// TSA_24936580121000 — fused temporal self-attention, MI355X gfx950. Round 8.
// = Round 2 (best: 104.6us, clean FETCH/WRITE 135/135, 2 blocks/CU) with ONE
// change-set: plain __launch_bounds__(512) (every ",N" / 1024-thr variant got
// VGPR-clamped to 64 and spilled; R1's plain-512 got 88 clean) + deep load
// batching in P1 (16 in flight) and pre-issued residual re-reads around P4.

#define C_  128
#define T_  16
#define H_  64
#define W_  64
#define HW_ (H_*W_)
#define CO_ 160          // 16 q + 16 k + 128 v
#define WT_ 16           // w positions per block
#define NBLK 1024        // 4 b * 64 h * 4 wtiles
#define THW (T_*H_*W_)

typedef float  f32x4  __attribute__((ext_vector_type(4)));
typedef short  bf16x4 __attribute__((ext_vector_type(4)));
typedef short  bf16x8 __attribute__((ext_vector_type(8)));

__device__ __forceinline__ unsigned short f2bf(float f) {
    union { float f; unsigned u; } v; v.f = f;
    unsigned r = v.u + 0x7fffu + ((v.u >> 16) & 1u);   // RNE
    return (unsigned short)(r >> 16);
}
__device__ __forceinline__ float bf2f(unsigned short s) {
    union { unsigned u; float f; } v; v.u = ((unsigned)s) << 16;
    return v.f;
}

// ---------------- prepack: fp32 weights -> bf16 W2[160][128], biases b2[160] ----
__global__ __launch_bounds__(256) void tsa_prepack(
        const float* __restrict__ qw, const float* __restrict__ qb,
        const float* __restrict__ kw, const float* __restrict__ kb,
        const float* __restrict__ vw, const float* __restrict__ vb,
        unsigned short* __restrict__ W2, float* __restrict__ b2) {
    int i = blockIdx.x * 256 + threadIdx.x;      // 80*256 == 20480 == 160*128
    int o = i >> 7, c = i & 127;
    float v = (o < 16) ? qw[o * C_ + c] : (o < 32) ? kw[(o - 16) * C_ + c]
                                                   : vw[(o - 32) * C_ + c];
    W2[i] = f2bf(v);
    if (i < CO_) b2[i] = (i < 16) ? qb[i] : (i < 32) ? kb[i - 16] : vb[i - 32];
}

// ---------------- LDS geometry (shorts) — ONE buffer, three time-shared views --
// x-stage:  [pos=16][t=16][c=128]  pos-stride PS=2184, t-stride TS=136 (34944 sh)
// qk:       [pos=16][2][t=16][o=16] = 8192 sh (aliases stage pos 0..3 region)
// out:      [t=16][w=16][c=128]    t-stride 2116, w-stride 132        (33856 sh)
#define PS 2184
#define TS 136
#define IDX_X(pos, t, c)      ((pos) * PS + (t) * TS + (c))
#define IDX_QK(pos, qk, t, o) (((((pos) * 2 + (qk)) * T_ + (t)) * 16) + (o))
#define OS_W 132
#define OS_T 2116
#define IDX_O(t, w, c)        ((t) * OS_T + (w) * OS_W + (c))
#define BUF_SH (T_ * PS)      // 34944 shorts = 69888 B -> 2 blocks/CU

// ---------------- main fused kernel --------------------------------------------
__global__ __launch_bounds__(512) void tsa_main(
        const float* __restrict__ x, const unsigned short* __restrict__ W2,
        const float* __restrict__ b2, const float* __restrict__ gamma,
        float* __restrict__ y) {

    __shared__ __align__(16) unsigned short buf[BUF_SH];

    // XCD-chunked swizzle (nwg=1024 % 8 == 0): 4 wtiles of one (b,h) row share an XCD.
    int bid  = blockIdx.x;
    int work = (bid & 7) * (NBLK / 8) + (bid >> 3);
    int bh = work >> 2;
    int wt = work & 3;
    int b  = bh >> 6, h = bh & 63;
    int w0 = wt * WT_;

    const size_t base = (size_t)b * C_ * THW + (size_t)h * W_ + w0;
    const float* xb = x + base;
    float*       yb = y + base;

    const int tid = threadIdx.x;
    const int wq  = tid & 3;          // 16B segment within the 64B w-row
    const int cs  = tid >> 2;         // channel 0..127
    const float g = gamma[0];

    const int wv  = tid >> 6;         // wave 0..7 -> positions wv*2, wv*2+1
    const int lr  = tid & 15;
    const int grp = (tid & 63) >> 4;

    // ---- phase 1: stage x tile -> bf16 LDS [pos][t][c]; 16 loads in flight --
    {
        const float* xcol = xb + (size_t)cs * THW + wq * 4;
        f32x4 xrA[8], xrB[8];
        #pragma unroll
        for (int t = 0; t < 8; ++t) xrA[t] = *(const f32x4*)(xcol + t * HW_);
        #pragma unroll
        for (int t = 0; t < 8; ++t) xrB[t] = *(const f32x4*)(xcol + (t + 8) * HW_);
        #pragma unroll
        for (int t = 0; t < 8; ++t) {
            #pragma unroll
            for (int e = 0; e < 4; ++e)
                buf[IDX_X(wq * 4 + e, t, cs)] = f2bf(xrA[t][e]);
        }
        #pragma unroll
        for (int t = 0; t < 8; ++t) {
            #pragma unroll
            for (int e = 0; e < 4; ++e)
                buf[IDX_X(wq * 4 + e, t + 8, cs)] = f2bf(xrB[t][e]);
        }
    }

    float biasv[10];
    #pragma unroll
    for (int nt = 0; nt < 10; ++nt) biasv[nt] = b2[nt * 16 + lr];

    __syncthreads();   // B1: stage complete

    // ---- phase 2 pre: A-fragments (x[t][c]) to registers --------------------
    bf16x8 afrag[2][4];
    #pragma unroll
    for (int p = 0; p < 2; ++p)
        #pragma unroll
        for (int ks = 0; ks < 4; ++ks)
            afrag[p][ks] = *(const bf16x8*)&buf[IDX_X(wv * 2 + p, lr, ks * 32 + grp * 8)];

    __syncthreads();   // B1.5: qk region aliases stage pos 0..3 — all reads done

    // ---- phase 2: qkv projection (mfma 16x16x32 bf16) -----------------------
    // v stays in registers: proj D-layout (col=o=lr, row=t=grp*4+r) IS the PV
    // A-layout (row=c=lr, k=j=grp*4+r) for the same lane.
    bf16x4 vreg[2][8];
    #pragma unroll
    for (int nt = 0; nt < 10; ++nt) {
        f32x4 acc0 = (f32x4){0.f, 0.f, 0.f, 0.f};
        f32x4 acc1 = (f32x4){0.f, 0.f, 0.f, 0.f};
        #pragma unroll
        for (int ks = 0; ks < 4; ++ks) {
            bf16x8 wf = *(const bf16x8*)&W2[(nt * 16 + lr) * C_ + ks * 32 + grp * 8];
            acc0 = __builtin_amdgcn_mfma_f32_16x16x32_bf16(afrag[0][ks], wf, acc0, 0, 0, 0);
            acc1 = __builtin_amdgcn_mfma_f32_16x16x32_bf16(afrag[1][ks], wf, acc1, 0, 0, 0);
        }
        if (nt < 2) {                 // q/k -> LDS (cross-lane transpose needed)
            #pragma unroll
            for (int r = 0; r < 4; ++r) {
                buf[IDX_QK(wv * 2 + 0, nt, grp * 4 + r, lr)] = f2bf(acc0[r] + biasv[nt]);
                buf[IDX_QK(wv * 2 + 1, nt, grp * 4 + r, lr)] = f2bf(acc1[r] + biasv[nt]);
            }
        } else {                      // v -> registers (bf16 packed)
            bf16x4 p0, p1;
            #pragma unroll
            for (int r = 0; r < 4; ++r) {
                p0[r] = (short)f2bf(acc0[r] + biasv[nt]);
                p1[r] = (short)f2bf(acc1[r] + biasv[nt]);
            }
            vreg[0][nt - 2] = p0;
            vreg[1][nt - 2] = p1;
        }
    }
    __syncthreads();   // B2: qk visible

    // ---- phase 3: scores^T -> softmax -> PV -> pack out bf16 ----------------
    bf16x4 obf[2][8];
    #pragma unroll
    for (int p = 0; p < 2; ++p) {
        int pos = wv * 2 + p;
        bf16x4 kf = *(const bf16x4*)&buf[IDX_QK(pos, 1, lr, grp * 4)];
        bf16x4 qf = *(const bf16x4*)&buf[IDX_QK(pos, 0, lr, grp * 4)];
        f32x4 s = (f32x4){0.f, 0.f, 0.f, 0.f};
        s = __builtin_amdgcn_mfma_f32_16x16x16bf16_1k(kf, qf, s, 0, 0, 0);
        float mx = fmaxf(fmaxf(s[0], s[1]), fmaxf(s[2], s[3]));
        mx = fmaxf(mx, __shfl_xor(mx, 16));
        mx = fmaxf(mx, __shfl_xor(mx, 32));
        float e0 = __expf(s[0] - mx), e1 = __expf(s[1] - mx);
        float e2 = __expf(s[2] - mx), e3 = __expf(s[3] - mx);
        float sm = e0 + e1 + e2 + e3;
        sm += __shfl_xor(sm, 16);
        sm += __shfl_xor(sm, 32);
        float inv = 1.0f / sm;
        bf16x4 pf;
        pf[0] = (short)f2bf(e0 * inv); pf[1] = (short)f2bf(e1 * inv);
        pf[2] = (short)f2bf(e2 * inv); pf[3] = (short)f2bf(e3 * inv);
        #pragma unroll
        for (int ct = 0; ct < 8; ++ct) {
            f32x4 z = (f32x4){0.f, 0.f, 0.f, 0.f};
            z = __builtin_amdgcn_mfma_f32_16x16x16bf16_1k(vreg[p][ct], pf, z, 0, 0, 0);
            bf16x4 ob;
            #pragma unroll
            for (int r = 0; r < 4; ++r) ob[r] = (short)f2bf(z[r]);
            obf[p][ct] = ob;
        }
    }
    __syncthreads();   // B3: qk/stage reads done — buffer becomes out region

    // ---- phase 4: pre-issue first half of residual re-reads, then spill -----
    const float* xrow = xb + (size_t)cs * THW + wq * 4;
    f32x4 xpA[8];
    #pragma unroll
    for (int t = 0; t < 8; ++t) xpA[t] = *(const f32x4*)(xrow + t * HW_);

    #pragma unroll
    for (int p = 0; p < 2; ++p)
        #pragma unroll
        for (int ct = 0; ct < 8; ++ct)
            *(bf16x4*)&buf[IDX_O(lr, wv * 2 + p, ct * 16 + grp * 4)] = obf[p][ct];
    __syncthreads();   // B4

    // ---- phase 5: y = gamma*out + x (exact fp32 residual) -------------------
    {
        float* yrow = yb + (size_t)cs * THW + wq * 4;
        f32x4 xpB[8];
        #pragma unroll
        for (int t = 0; t < 8; ++t) xpB[t] = *(const f32x4*)(xrow + (t + 8) * HW_);
        #pragma unroll
        for (int t = 0; t < 8; ++t) {
            f32x4 rv;
            #pragma unroll
            for (int e = 0; e < 4; ++e)
                rv[e] = fmaf(g, bf2f(buf[IDX_O(t, wq * 4 + e, cs)]), xpA[t][e]);
            *(f32x4*)(yrow + t * HW_) = rv;
        }
        #pragma unroll
        for (int t = 0; t < 8; ++t) {
            f32x4 rv;
            #pragma unroll
            for (int e = 0; e < 4; ++e)
                rv[e] = fmaf(g, bf2f(buf[IDX_O(t + 8, wq * 4 + e, cs)]), xpB[t][e]);
            *(f32x4*)(yrow + (t + 8) * HW_) = rv;
        }
    }
}

// ---------------- launch --------------------------------------------------------
extern "C" void kernel_launch(void* const* d_in, const int* in_sizes, int n_in,
                              void* d_out, int out_size, void* d_ws, size_t ws_size,
                              hipStream_t stream) {
    const float* x  = (const float*)d_in[0];
    const float* qw = (const float*)d_in[1];
    const float* qb = (const float*)d_in[2];
    const float* kw = (const float*)d_in[3];
    const float* kb = (const float*)d_in[4];
    const float* vw = (const float*)d_in[5];
    const float* vb = (const float*)d_in[6];
    const float* gm = (const float*)d_in[7];
    float* y = (float*)d_out;

    unsigned short* W2 = (unsigned short*)d_ws;                  // 160*128 bf16
    float* b2 = (float*)((char*)d_ws + CO_ * C_ * sizeof(unsigned short));

    tsa_prepack<<<80, 256, 0, stream>>>(qw, qb, kw, kb, vw, vb, W2, b2);
    tsa_main<<<NBLK, 512, 0, stream>>>(x, W2, b2, gm, y);
}

// Round 9
// 101.222 us; speedup vs baseline: 3.1350x; 1.0338x over previous
//
#include <hip/hip_runtime.h>

// TSA_24936580121000 — fused temporal self-attention, MI355X gfx950. Round 9.
// MSHR/piece-size experiment, spill-free: WT=32 -> every global piece (stage
// read, residual read, y write) is 128B contiguous (R4 idea, minus the spills).
// 512 thr plain LB (VGPR cap ~76-88, all state transient <= ~80), wave-private
// qk scratch (no barrier), outT written into the position's own dead stage slot
// (no extra LDS, no extra barrier) -> 2 barriers total. 1 block/CU, 512 blocks.

#define C_  128
#define T_  16
#define H_  64
#define W_  64
#define HW_ (H_*W_)
#define CO_ 160          // 16 q + 16 k + 128 v
#define WT_ 32           // w positions per block
#define NBLK 512         // 4 b * 64 h * 2 wtiles
#define THW (T_*H_*W_)

typedef float  f32x4  __attribute__((ext_vector_type(4)));
typedef short  bf16x4 __attribute__((ext_vector_type(4)));
typedef short  bf16x8 __attribute__((ext_vector_type(8)));

__device__ __forceinline__ unsigned short f2bf(float f) {
    union { float f; unsigned u; } v; v.f = f;
    unsigned r = v.u + 0x7fffu + ((v.u >> 16) & 1u);   // RNE
    return (unsigned short)(r >> 16);
}
__device__ __forceinline__ float bf2f(unsigned short s) {
    union { unsigned u; float f; } v; v.u = ((unsigned)s) << 16;
    return v.f;
}

// ---------------- prepack: fp32 weights -> bf16 W2[160][128], biases b2[160] ----
__global__ __launch_bounds__(256) void tsa_prepack(
        const float* __restrict__ qw, const float* __restrict__ qb,
        const float* __restrict__ kw, const float* __restrict__ kb,
        const float* __restrict__ vw, const float* __restrict__ vb,
        unsigned short* __restrict__ W2, float* __restrict__ b2) {
    int i = blockIdx.x * 256 + threadIdx.x;      // 80*256 == 20480 == 160*128
    int o = i >> 7, c = i & 127;
    float v = (o < 16) ? qw[o * C_ + c] : (o < 32) ? kw[(o - 16) * C_ + c]
                                                   : vw[(o - 32) * C_ + c];
    W2[i] = f2bf(v);
    if (i < CO_) b2[i] = (i < 16) ? qb[i] : (i < 32) ? kb[i - 16] : vb[i - 32];
}

// ---------------- LDS geometry (shorts) ----------------------------------------
// stage/out (time-shared PER SLOT): [pos=32][t=16][c=128 swz] pos-stride 2184
//   (dw stride 1092 == 4 mod 32: banks spread; 4368B == 0 mod 16: b128 ok),
//   t-stride 136. c stored XOR-swizzled: loc = c ^ ((pos>>2)<<3).
// qkscr: wave-private [wv=8][qk=2][t=16][o-stride 20]  (no barrier needed)
// bias:  f32[160]
#define PS 2184
#define TS 136
#define IDX_X(pos, t, c)   ((pos) * PS + (t) * TS + (c))
#define QOFF 69888
#define QIDX(wv, qk, t, o) (QOFF + (wv) * 640 + (qk) * 320 + (t) * 20 + (o))
#define BIAS_OFF 75008
#define BUF_SH 75328          // 150656 B <= 160 KiB -> 1 block/CU

// ---------------- main fused kernel --------------------------------------------
__global__ __launch_bounds__(512) void tsa_main(
        const float* __restrict__ x, const unsigned short* __restrict__ W2,
        const float* __restrict__ b2, const float* __restrict__ gamma,
        float* __restrict__ y) {

    __shared__ __align__(16) unsigned short buf[BUF_SH];
    float* bias_lds = (float*)&buf[BIAS_OFF];

    // XCD-chunked swizzle (nwg=512 % 8 == 0): the 2 wtiles of a (b,h) row and
    // adjacent h land on one XCD.
    int bid  = blockIdx.x;
    int work = (bid & 7) * (NBLK / 8) + (bid >> 3);
    int bh = work >> 1;
    int wt = work & 1;
    int b  = bh >> 6, h = bh & 63;
    int w0 = wt * WT_;

    const size_t base = (size_t)b * C_ * THW + (size_t)h * W_ + w0;
    const float* xb = x + base;
    float*       yb = y + base;

    const int tid = threadIdx.x;
    const int seg = tid & 7;          // 16B segment of the 128B w-row
    const int cs0 = tid >> 3;         // channel 0..63 (+64 on round 1)
    const float g = gamma[0];

    const int wv  = tid >> 6;         // wave 0..7 -> positions wv*4 .. wv*4+3
    const int lr  = tid & 15;
    const int grp = (tid & 63) >> 4;

    if (tid < CO_) bias_lds[tid] = b2[tid];

    // ---- P1: stage x tile -> bf16 LDS [pos][t][c-swz]; 128B read pieces -----
    #pragma unroll
    for (int r = 0; r < 2; ++r) {
        const int cs  = cs0 + 64 * r;
        const int loc = cs ^ (seg << 3);
        const float* xcol = xb + (size_t)cs * THW + seg * 4;
        f32x4 xa[8];
        #pragma unroll
        for (int t = 0; t < 8; ++t) xa[t] = *(const f32x4*)(xcol + t * HW_);
        #pragma unroll
        for (int t = 0; t < 8; ++t)
            #pragma unroll
            for (int e = 0; e < 4; ++e)
                buf[IDX_X(seg * 4 + e, t, loc)] = f2bf(xa[t][e]);
        #pragma unroll
        for (int t = 0; t < 8; ++t) xa[t] = *(const f32x4*)(xcol + (t + 8) * HW_);
        #pragma unroll
        for (int t = 0; t < 8; ++t)
            #pragma unroll
            for (int e = 0; e < 4; ++e)
                buf[IDX_X(seg * 4 + e, t + 8, loc)] = f2bf(xa[t][e]);
    }
    __syncthreads();   // B1 (one of only two barriers)

    // ---- per-wave: project + attend 4 positions, all wave-local -------------
    const int swz = wv << 3;          // pos>>2 == wv for this wave's positions
    for (int pp = 0; pp < 4; ++pp) {
        const int pos = wv * 4 + pp;

        // afrag preload; after this the slot is dead (only this wave reads it)
        bf16x8 afrag[4];
        #pragma unroll
        for (int ks = 0; ks < 4; ++ks)
            afrag[ks] = *(const bf16x8*)&buf[IDX_X(pos, lr, (ks * 32 + grp * 8) ^ swz)];

        // qkv projection (mfma 16x16x32): q/k -> wave-private LDS scratch,
        // v -> regs (proj D-layout == PV A-layout for the same lane)
        bf16x4 vreg[8];
        #pragma unroll
        for (int nt = 0; nt < 10; ++nt) {
            f32x4 acc = (f32x4){0.f, 0.f, 0.f, 0.f};
            #pragma unroll
            for (int ks = 0; ks < 4; ++ks) {
                bf16x8 wf = *(const bf16x8*)&W2[(nt * 16 + lr) * C_ + ks * 32 + grp * 8];
                acc = __builtin_amdgcn_mfma_f32_16x16x32_bf16(afrag[ks], wf, acc, 0, 0, 0);
            }
            float bv = bias_lds[nt * 16 + lr];
            if (nt < 2) {
                #pragma unroll
                for (int rr = 0; rr < 4; ++rr)
                    buf[QIDX(wv, nt, grp * 4 + rr, lr)] = f2bf(acc[rr] + bv);
            } else {
                bf16x4 pk;
                #pragma unroll
                for (int rr = 0; rr < 4; ++rr) pk[rr] = (short)f2bf(acc[rr] + bv);
                vreg[nt - 2] = pk;
            }
        }

        // scores^T -> softmax -> PV (wave-local; lgkmcnt orders qkscr)
        bf16x4 kf = *(const bf16x4*)&buf[QIDX(wv, 1, lr, grp * 4)];
        bf16x4 qf = *(const bf16x4*)&buf[QIDX(wv, 0, lr, grp * 4)];
        f32x4 s = (f32x4){0.f, 0.f, 0.f, 0.f};
        s = __builtin_amdgcn_mfma_f32_16x16x16bf16_1k(kf, qf, s, 0, 0, 0);
        float mx = fmaxf(fmaxf(s[0], s[1]), fmaxf(s[2], s[3]));
        mx = fmaxf(mx, __shfl_xor(mx, 16));
        mx = fmaxf(mx, __shfl_xor(mx, 32));
        float e0 = __expf(s[0] - mx), e1 = __expf(s[1] - mx);
        float e2 = __expf(s[2] - mx), e3 = __expf(s[3] - mx);
        float sm = e0 + e1 + e2 + e3;
        sm += __shfl_xor(sm, 16);
        sm += __shfl_xor(sm, 32);
        float inv = 1.0f / sm;
        bf16x4 pf;
        pf[0] = (short)f2bf(e0 * inv); pf[1] = (short)f2bf(e1 * inv);
        pf[2] = (short)f2bf(e2 * inv); pf[3] = (short)f2bf(e3 * inv);

        // outT -> the position's own (dead) stage slot, same swizzle
        #pragma unroll
        for (int ct = 0; ct < 8; ++ct) {
            f32x4 z = (f32x4){0.f, 0.f, 0.f, 0.f};
            z = __builtin_amdgcn_mfma_f32_16x16x16bf16_1k(vreg[ct], pf, z, 0, 0, 0);
            bf16x4 ob;
            #pragma unroll
            for (int rr = 0; rr < 4; ++rr) ob[rr] = (short)f2bf(z[rr]);
            *(bf16x4*)&buf[IDX_X(pos, lr, (ct * 16 + grp * 4) ^ swz)] = ob;
        }
    }
    __syncthreads();   // B2: all outT slots visible

    // ---- P5: y = gamma*out + x (exact fp32 residual); 128B pieces -----------
    #pragma unroll
    for (int r = 0; r < 2; ++r) {
        const int cs  = cs0 + 64 * r;
        const int loc = cs ^ (seg << 3);   // matches writer: pos>>2 == seg here
        const float* xrow = xb + (size_t)cs * THW + seg * 4;
        float*       yrow = yb + (size_t)cs * THW + seg * 4;
        f32x4 xa[8], xc[8];
        #pragma unroll
        for (int t = 0; t < 8; ++t) xa[t] = *(const f32x4*)(xrow + t * HW_);
        #pragma unroll
        for (int t = 0; t < 8; ++t) xc[t] = *(const f32x4*)(xrow + (t + 8) * HW_);
        #pragma unroll
        for (int t = 0; t < 8; ++t) {
            f32x4 rv;
            #pragma unroll
            for (int e = 0; e < 4; ++e)
                rv[e] = fmaf(g, bf2f(buf[IDX_X(seg * 4 + e, t, loc)]), xa[t][e]);
            *(f32x4*)(yrow + t * HW_) = rv;
        }
        #pragma unroll
        for (int t = 0; t < 8; ++t) {
            f32x4 rv;
            #pragma unroll
            for (int e = 0; e < 4; ++e)
                rv[e] = fmaf(g, bf2f(buf[IDX_X(seg * 4 + e, t + 8, loc)]), xc[t][e]);
            *(f32x4*)(yrow + (t + 8) * HW_) = rv;
        }
    }
}

// ---------------- launch --------------------------------------------------------
extern "C" void kernel_launch(void* const* d_in, const int* in_sizes, int n_in,
                              void* d_out, int out_size, void* d_ws, size_t ws_size,
                              hipStream_t stream) {
    const float* x  = (const float*)d_in[0];
    const float* qw = (const float*)d_in[1];
    const float* qb = (const float*)d_in[2];
    const float* kw = (const float*)d_in[3];
    const float* kb = (const float*)d_in[4];
    const float* vw = (const float*)d_in[5];
    const float* vb = (const float*)d_in[6];
    const float* gm = (const float*)d_in[7];
    float* y = (float*)d_out;

    unsigned short* W2 = (unsigned short*)d_ws;                  // 160*128 bf16
    float* b2 = (float*)((char*)d_ws + CO_ * C_ * sizeof(unsigned short));

    tsa_prepack<<<80, 256, 0, stream>>>(qw, qb, kw, kb, vw, vb, W2, b2);
    tsa_main<<<NBLK, 512, 0, stream>>>(x, W2, b2, gm, y);
}